// Round 2
// baseline (79.505 us; speedup 1.0000x reference)
//
#include <hip/hip_runtime.h>

// TemporalNorm: causal rolling-window (W=128) mean/var norm over time, per (b,d).
// x: [B,T,D] f32, weight/bias: [D] f32, out: [B,T,D] f32.
constexpr int Bb  = 32;
constexpr int Tt  = 4096;
constexpr int Dd  = 256;
constexpr int Ww  = 128;
constexpr float EPSF = 1e-5f;

constexpr int CT  = 64;           // time chunk per block (smaller -> more TLP)
constexpr int NC  = Tt / CT;      // 64 chunks
constexpr int NWG = Bb * NC;      // 2048 blocks = 8 blocks/CU = 32 waves/CU

__global__ __launch_bounds__(256, 8)
void TemporalNorm_kernel(const float* __restrict__ x,
                         const float* __restrict__ wgt,
                         const float* __restrict__ bia,
                         float* __restrict__ out) {
    // XCD-contiguous swizzle: HW round-robins launch index i over 8 XCDs;
    // remap so each XCD owns a contiguous range of (b, chunk). NWG%8==0 -> bijective.
    const int i  = blockIdx.x;
    const int lb = (i & 7) * (NWG / 8) + (i >> 3);
    const int b  = lb / NC;
    const int c  = lb % NC;
    const int d  = threadIdx.x;
    const int t0 = c * CT;

    const float* __restrict__ xb = x   + (size_t)b * Tt * Dd + d;
    float*       __restrict__ ob = out + (size_t)b * Tt * Dd + d;
    const float w  = wgt[d];
    const float bi = bia[d];

    float s1 = 0.0f, s2 = 0.0f;

    if (t0 >= Ww) {
        // ---- steady-state chunks: window always full (n = W) ----
        // warm-up: sum over [t0-W, t0); two accumulator pairs to cut dep chain
        float u1 = 0.0f, u2 = 0.0f;
        for (int t = t0 - Ww; t < t0; t += 4) {
            float a0 = xb[(t + 0) * Dd];
            float a1 = xb[(t + 1) * Dd];
            float a2 = xb[(t + 2) * Dd];
            float a3 = xb[(t + 3) * Dd];
            s1 += a0 + a1;  u1 += a2 + a3;
            s2 += a0 * a0 + a1 * a1;  u2 += a2 * a2 + a3 * a3;
        }
        s1 += u1;  s2 += u2;
        const float rn = 1.0f / (float)Ww;   // exact (1/128)
        for (int t = t0; t < t0 + CT; t += 4) {
            // batch 8 independent loads for ILP
            float a0 = xb[(t + 0) * Dd];
            float a1 = xb[(t + 1) * Dd];
            float a2 = xb[(t + 2) * Dd];
            float a3 = xb[(t + 3) * Dd];
            float o0 = xb[(t + 0 - Ww) * Dd];
            float o1 = xb[(t + 1 - Ww) * Dd];
            float o2 = xb[(t + 2 - Ww) * Dd];
            float o3 = xb[(t + 3 - Ww) * Dd];

            s1 += a0 - o0; s2 += a0 * a0 - o0 * o0;
            {
                float loc = s1 * rn;
                float var = s2 * rn - loc * loc;
                float inv = rsqrtf(var + EPSF);
                __builtin_nontemporal_store((a0 - loc) * inv * w + bi, &ob[(t + 0) * Dd]);
            }
            s1 += a1 - o1; s2 += a1 * a1 - o1 * o1;
            {
                float loc = s1 * rn;
                float var = s2 * rn - loc * loc;
                float inv = rsqrtf(var + EPSF);
                __builtin_nontemporal_store((a1 - loc) * inv * w + bi, &ob[(t + 1) * Dd]);
            }
            s1 += a2 - o2; s2 += a2 * a2 - o2 * o2;
            {
                float loc = s1 * rn;
                float var = s2 * rn - loc * loc;
                float inv = rsqrtf(var + EPSF);
                __builtin_nontemporal_store((a2 - loc) * inv * w + bi, &ob[(t + 2) * Dd]);
            }
            s1 += a3 - o3; s2 += a3 * a3 - o3 * o3;
            {
                float loc = s1 * rn;
                float var = s2 * rn - loc * loc;
                float inv = rsqrtf(var + EPSF);
                __builtin_nontemporal_store((a3 - loc) * inv * w + bi, &ob[(t + 3) * Dd]);
            }
        }
    } else {
        // ---- early chunks (t0 < W): growing window, n = min(t+1, W) ----
        // warm-up over [0, t0)
        for (int t = 0; t < t0; ++t) {
            float a = xb[t * Dd];
            s1 += a; s2 += a * a;
        }
        for (int t = t0; t < t0 + CT; ++t) {
            float a = xb[t * Dd];
            s1 += a; s2 += a * a;
            if (t >= Ww) {
                float o = xb[(t - Ww) * Dd];
                s1 -= o; s2 -= o * o;
            }
            float n   = (float)((t + 1 < Ww) ? (t + 1) : Ww);
            float rn  = 1.0f / n;
            float loc = s1 * rn;
            float var = s2 * rn - loc * loc;
            float inv = rsqrtf(var + EPSF);
            __builtin_nontemporal_store((a - loc) * inv * w + bi, &ob[t * Dd]);
        }
    }
}

extern "C" void kernel_launch(void* const* d_in, const int* in_sizes, int n_in,
                              void* d_out, int out_size, void* d_ws, size_t ws_size,
                              hipStream_t stream) {
    const float* x   = (const float*)d_in[0];
    const float* wgt = (const float*)d_in[1];
    const float* bia = (const float*)d_in[2];
    float* out = (float*)d_out;

    hipLaunchKernelGGL(TemporalNorm_kernel, dim3(NWG), dim3(256), 0, stream,
                       x, wgt, bia, out);
}

// Round 3
// 61.913 us; speedup vs baseline: 1.2841x; 1.2841x over previous
//
#include <hip/hip_runtime.h>

// TemporalNorm: causal rolling-window (W=128) mean/var norm over time, per (b,d).
// x: [B,T,D] f32, weight/bias: [D] f32, out: [B,T,D] f32.
constexpr int Bb  = 32;
constexpr int Tt  = 4096;
constexpr int Dd  = 256;
constexpr int Ww  = 128;
constexpr float EPSF = 1e-5f;

constexpr int CT  = 128;          // time chunk per block-slice (W/CT=1 -> min warm-up amplification)
constexpr int NC  = Tt / CT;      // 32 chunks
constexpr int TPC = Dd / 2;       // 128 threads per chunk, float2 per thread
constexpr int CPB = 2;            // 2 chunks per 256-thread block
constexpr int NWG = Bb * NC / CPB; // 512 blocks -> 2 blocks/CU, 16 waves/CU

__global__ __launch_bounds__(256, 4)
void TemporalNorm_kernel(const float* __restrict__ x,
                         const float* __restrict__ wgt,
                         const float* __restrict__ bia,
                         float* __restrict__ out) {
    // XCD-contiguous swizzle (NWG % 8 == 0 -> bijective): each XCD gets a
    // contiguous run of (b, chunk-pair) so neighboring chunks share its L2.
    const int i  = blockIdx.x;
    const int lb = (i & 7) * (NWG / 8) + (i >> 3);
    const int b     = lb / (NC / CPB);
    const int cpair = lb % (NC / CPB);
    const int sub   = threadIdx.x / TPC;       // which chunk of the pair
    const int d2    = threadIdx.x % TPC;       // float2 channel index
    const int c  = cpair * CPB + sub;
    const int t0 = c * CT;

    const float2* __restrict__ xb = reinterpret_cast<const float2*>(x   + (size_t)b * Tt * Dd) + d2;
    float2*       __restrict__ ob = reinterpret_cast<float2*>      (out + (size_t)b * Tt * Dd) + d2;
    const float wx = wgt[2 * d2],     wy = wgt[2 * d2 + 1];
    const float bx = bia[2 * d2],     by = bia[2 * d2 + 1];
    constexpr int S = Dd / 2;                  // float2 stride per time step

    float s1x = 0.f, s2x = 0.f, s1y = 0.f, s2y = 0.f;

    if (t0 >= Ww) {
        // ---- steady-state chunks: window always full (n = W) ----
        // warm-up over [t0-W, t0), dual accumulators per channel to cut dep chain
        float u1x = 0.f, u2x = 0.f, u1y = 0.f, u2y = 0.f;
        for (int t = t0 - Ww; t < t0; t += 4) {
            float2 a0 = xb[(t + 0) * S];
            float2 a1 = xb[(t + 1) * S];
            float2 a2 = xb[(t + 2) * S];
            float2 a3 = xb[(t + 3) * S];
            s1x += a0.x + a1.x;  u1x += a2.x + a3.x;
            s2x += a0.x * a0.x + a1.x * a1.x;  u2x += a2.x * a2.x + a3.x * a3.x;
            s1y += a0.y + a1.y;  u1y += a2.y + a3.y;
            s2y += a0.y * a0.y + a1.y * a1.y;  u2y += a2.y * a2.y + a3.y * a3.y;
        }
        s1x += u1x; s2x += u2x; s1y += u1y; s2y += u2y;

        const float rn = 1.0f / (float)Ww;     // exact (1/128)
        auto step = [&](float a, float o, float& s1, float& s2, float w, float bi) -> float {
            s1 += a - o;
            s2 += a * a - o * o;
            float loc = s1 * rn;
            float var = s2 * rn - loc * loc;
            return (a - loc) * rsqrtf(var + EPSF) * w + bi;
        };

        for (int t = t0; t < t0 + CT; t += 4) {
            // 8 independent 8B loads in flight per group
            float2 a0 = xb[(t + 0) * S];
            float2 a1 = xb[(t + 1) * S];
            float2 a2 = xb[(t + 2) * S];
            float2 a3 = xb[(t + 3) * S];
            float2 o0 = xb[(t + 0 - Ww) * S];
            float2 o1 = xb[(t + 1 - Ww) * S];
            float2 o2 = xb[(t + 2 - Ww) * S];
            float2 o3 = xb[(t + 3 - Ww) * S];

            float2 r0, r1, r2, r3;
            r0.x = step(a0.x, o0.x, s1x, s2x, wx, bx);
            r0.y = step(a0.y, o0.y, s1y, s2y, wy, by);
            r1.x = step(a1.x, o1.x, s1x, s2x, wx, bx);
            r1.y = step(a1.y, o1.y, s1y, s2y, wy, by);
            r2.x = step(a2.x, o2.x, s1x, s2x, wx, bx);
            r2.y = step(a2.y, o2.y, s1y, s2y, wy, by);
            r3.x = step(a3.x, o3.x, s1x, s2x, wx, bx);
            r3.y = step(a3.y, o3.y, s1y, s2y, wy, by);

            ob[(t + 0) * S] = r0;
            ob[(t + 1) * S] = r1;
            ob[(t + 2) * S] = r2;
            ob[(t + 3) * S] = r3;
        }
    } else {
        // ---- chunk 0 (t0 == 0): growing window, n = t+1 (t < W always) ----
        for (int t = 0; t < CT; ++t) {
            float2 a = xb[t * S];
            s1x += a.x; s2x += a.x * a.x;
            s1y += a.y; s2y += a.y * a.y;
            float rn  = 1.0f / (float)(t + 1);
            float lx  = s1x * rn, ly = s1y * rn;
            float vx  = s2x * rn - lx * lx;
            float vy  = s2y * rn - ly * ly;
            float2 r;
            r.x = (a.x - lx) * rsqrtf(vx + EPSF) * wx + bx;
            r.y = (a.y - ly) * rsqrtf(vy + EPSF) * wy + by;
            ob[t * S] = r;
        }
    }
}

extern "C" void kernel_launch(void* const* d_in, const int* in_sizes, int n_in,
                              void* d_out, int out_size, void* d_ws, size_t ws_size,
                              hipStream_t stream) {
    const float* x   = (const float*)d_in[0];
    const float* wgt = (const float*)d_in[1];
    const float* bia = (const float*)d_in[2];
    float* out = (float*)d_out;

    hipLaunchKernelGGL(TemporalNorm_kernel, dim3(NWG), dim3(256), 0, stream,
                       x, wgt, bia, out);
}